// Round 19
// baseline (690.291 us; speedup 1.0000x reference)
//
#include <hip/hip_runtime.h>
#include <math.h>

#define EPSV 1e-5f

#if __has_builtin(__builtin_amdgcn_exp2f)
#define EXP2F(x) __builtin_amdgcn_exp2f(x)
#else
#define EXP2F(x) exp2f(x)
#endif
#if __has_builtin(__builtin_amdgcn_rcpf)
#define RCPF(x) __builtin_amdgcn_rcpf(x)
#else
#define RCPF(x) (1.0f/(x))
#endif

__device__ __forceinline__ float fsigmoid(float x){
  return RCPF(1.0f + EXP2F(-1.4426950408889634f * x));
}
__device__ __forceinline__ float ftanh(float x){
  return RCPF(0.5f + 0.5f * EXP2F(-2.8853900817779268f * x)) - 1.0f;
}
__device__ __forceinline__ unsigned short f2bf(float f){
  unsigned u = __float_as_uint(f);
  return (unsigned short)((u + 0x7FFFu + ((u >> 16) & 1u)) >> 16);
}
__device__ __forceinline__ float bf2f(unsigned short u){
  return __uint_as_float(((unsigned)u) << 16);
}

typedef __attribute__((ext_vector_type(8))) short bf16x8;
typedef __attribute__((ext_vector_type(4))) float f32x4;
typedef __attribute__((ext_vector_type(2))) _Float16 f16x2;
typedef __attribute__((ext_vector_type(8))) _Float16 f16x8;

#if __has_builtin(__builtin_amdgcn_fdot2)
#define FDOT2(a,b,c) __builtin_amdgcn_fdot2(a,b,c,false)
#else
__device__ __forceinline__ float FDOT2(f16x2 a, f16x2 b, float c){
  return c + (float)a[0]*(float)b[0] + (float)a[1]*(float)b[1];
}
#endif

__device__ __forceinline__ float dot8(f16x8 w, f16x8 h, float acc){
  f16x2 w0 = {w[0],w[1]}, w1 = {w[2],w[3]}, w2 = {w[4],w[5]}, w3 = {w[6],w[7]};
  f16x2 h0 = {h[0],h[1]}, h1 = {h[2],h[3]}, h2 = {h[4],h[5]}, h3 = {h[6],h[7]};
  acc = FDOT2(w0,h0,acc); acc = FDOT2(w1,h1,acc);
  acc = FDOT2(w2,h2,acc); acc = FDOT2(w3,h3,acc);
  return acc;
}

// ---------------- K1: fused conv1d(+bias, BN1 stats, x_bf emit) and weight converts.
__global__ __launch_bounds__(256) void k_convcvt(const float* __restrict__ x, const float* __restrict__ w,
        const float* __restrict__ cb, float* __restrict__ hp, float* __restrict__ s1g,
        float* __restrict__ s2g, unsigned short* __restrict__ x_bf,
        const float* __restrict__ wih, const float* __restrict__ qw, const float* __restrict__ kw,
        const float* __restrict__ vw, const float* __restrict__ whh,
        unsigned short* __restrict__ wih_bf, unsigned short* __restrict__ wqkv_bf,
        _Float16* __restrict__ whh_h){
  const int tid = threadIdx.x;
  if (blockIdx.x >= 1024){
    int i = (blockIdx.x - 1024)*256 + tid;
    if (i < 61440){ wih_bf[i] = f2bf(wih[i]); return; }
    int r = i - 61440;
    if (r < 16384){ wqkv_bf[r] = f2bf(qw[r]); return; }
    r -= 16384;
    if (r < 16384){ wqkv_bf[16384 + r] = f2bf(kw[r]); return; }
    r -= 16384;
    if (r < 16384){ wqkv_bf[32768 + r] = f2bf(vw[r]); return; }
    r -= 16384;
    if (r < 49152){ whh_h[r] = (_Float16)whh[r]; }
    return;
  }
  __shared__ float xs[32*321];
  __shared__ float ws[32*97];
  __shared__ float bs[32];
  const int t0 = (blockIdx.x >> 4) * 8;
  const int n0 = (blockIdx.x & 15) * 8;
  for (int idx = tid; idx < 32*10*32; idx += 256){
    int bq = idx / 320; int rem = idx - bq*320; int tt = rem >> 5; int i = rem & 31;
    int tg = t0 - 1 + tt;
    float v = 0.f;
    if (tg >= 0 && tg < 512) v = x[(bq*512 + tg)*32 + i];
    xs[bq*321 + tt*32 + i] = v;
  }
  for (int idx = tid; idx < 32*96; idx += 256){
    int row = idx / 96; int within = idx - row*96;
    int ss = row >> 3; int nl = row & 7;
    int c = ss*128 + n0 + nl;
    ws[row*97 + within] = w[c*96 + within];
  }
  if (tid < 32){
    int ss = tid >> 3, nl = tid & 7;
    bs[tid] = cb[ss*128 + n0 + nl];
  }
  __syncthreads();
  if ((blockIdx.x & 15) == 0){
    for (int idx = tid; idx < 32*8*32; idx += 256){
      int bq = idx >> 8; int rem = idx & 255; int tt = rem >> 5; int i = rem & 31;
      x_bf[(bq*512 + t0 + tt)*32 + i] = f2bf(xs[bq*321 + (tt+1)*32 + i]);
    }
  }
  const int b = tid & 31;
  const int nl = tid >> 5;
  float acc[4][8];
  #pragma unroll
  for (int ss = 0; ss < 4; ++ss){
    float bv = bs[ss*8 + nl];
    #pragma unroll
    for (int t = 0; t < 8; ++t) acc[ss][t] = bv;
  }
  for (int i = 0; i < 32; ++i){
    #pragma unroll
    for (int k = 0; k < 3; ++k){
      float w0 = ws[(0*8+nl)*97 + i*3 + k];
      float w1 = ws[(1*8+nl)*97 + i*3 + k];
      float w2 = ws[(2*8+nl)*97 + i*3 + k];
      float w3 = ws[(3*8+nl)*97 + i*3 + k];
      #pragma unroll
      for (int t = 0; t < 8; ++t){
        float xv = xs[b*321 + (t+k)*32 + i];
        acc[0][t] += xv*w0; acc[1][t] += xv*w1; acc[2][t] += xv*w2; acc[3][t] += xv*w3;
      }
    }
  }
  #pragma unroll
  for (int ss = 0; ss < 4; ++ss){
    int n = n0 + nl;
    float s1 = 0.f, s2 = 0.f;
    #pragma unroll
    for (int t = 0; t < 8; ++t){
      float v = acc[ss][t];
      int s = (t0 + t)*4 + ss;
      hp[s*4096 + n*32 + b] = v;
      s1 += v; s2 += v*v;
    }
    #pragma unroll
    for (int off = 1; off < 32; off <<= 1){
      s1 += __shfl_xor(s1, off);
      s2 += __shfl_xor(s2, off);
    }
    if (b == 0){
      int c = ss*128 + n;
      atomicAdd(&s1g[c], s1);
      atomicAdd(&s2g[c], s2);
    }
  }
}

// ---------------- K3: fused BN1-finalize + LIF1 + BN2 + LIF2 + downsample -> md_t
// 128 blocks x 32 threads (1 n-chain/block, lanes = batch); 3-deep hp prefetch.
__global__ __launch_bounds__(32) void k_lif(const float* __restrict__ hp,
        const float* __restrict__ s1g, const float* __restrict__ s2g,
        const float* __restrict__ g1v, const float* __restrict__ b1v,
        const float* __restrict__ beta1, const float* __restrict__ g2v, const float* __restrict__ b2v,
        const float* __restrict__ beta2, unsigned short* __restrict__ md_t){
  const int tid = threadIdx.x;
  const int b = tid & 31;
  const int n = blockIdx.x;
  float a1r[4], b1r[4];
  #pragma unroll
  for (int ss = 0; ss < 4; ++ss){
    int c = ss*128 + n;
    float m = s1g[c] * (1.f/16384.f);
    float v = s2g[c] * (1.f/16384.f) - m*m;
    float sc = g1v[c] * rsqrtf(v + EPSV);
    a1r[ss] = sc;
    b1r[ss] = b1v[c] - m*sc;
  }
  float be1 = fminf(fmaxf(beta1[n], 0.f), 0.99f);
  float be2 = fminf(fmaxf(beta2[n], 0.f), 0.99f);
  float g2 = g2v[n], bb2 = b2v[n];
  float m1 = 0.f, r1 = 0.f, m2 = 0.f, r2 = 0.f;
  const float* base = hp + n*32 + b;
  float c0 = base[0], c1 = base[4096], c2 = base[2*4096], c3 = base[3*4096];
  const float* p1 = base + 16384;
  float d0 = p1[0], d1 = p1[4096], d2 = p1[2*4096], d3 = p1[3*4096];
  const float* p2 = base + 2*16384;
  float e0 = p2[0], e1 = p2[4096], e2 = p2[2*4096], e3 = p2[3*4096];

#define LIF_STEP(CV, A1R, B1R) { \
    float x1 = CV*A1R + B1R; \
    m1 = be1*m1 + x1 - r1; \
    bool sp = (m1 > 1.0f); \
    unsigned long long mk = __ballot(sp); \
    float spk = sp ? 1.f : 0.f; r1 = spk; \
    float mean = (float)__popc((unsigned)mk) * 0.03125f; \
    float var = mean - mean*mean; \
    float h2 = (spk - mean) * rsqrtf(var + EPSV) * g2 + bb2; \
    m2 = be2*m2 + h2 - r2; \
    r2 = (m2 > 1.0f) ? 1.f : 0.f; \
    accd += m2; }

  for (int t = 0; t < 512; ++t){
    float f0 = 0.f, f1 = 0.f, f2 = 0.f, f3 = 0.f;
    if (t < 509){
      const float* nb = base + (size_t)(t+3)*16384;
      f0 = nb[0]; f1 = nb[4096]; f2 = nb[2*4096]; f3 = nb[3*4096];
    }
    float accd = 0.f;
    LIF_STEP(c0, a1r[0], b1r[0])
    LIF_STEP(c1, a1r[1], b1r[1])
    LIF_STEP(c2, a1r[2], b1r[2])
    LIF_STEP(c3, a1r[3], b1r[3])
    md_t[((t*128) + n)*32 + b] = f2bf(accd * 0.25f);
    c0 = d0; c1 = d1; c2 = d2; c3 = d3;
    d0 = e0; d1 = e1; d2 = e2; d3 = e3;
    e0 = f0; e1 = f1; e2 = f2; e3 = f3;
  }
#undef LIF_STEP
}

// ---------------- K4: gi2b (bf16 ushort4 {r,z,n,0}) = concat(x, md) @ W_ih^T + b_ih via MFMA.
__global__ __launch_bounds__(256) void k_mm_gi(const unsigned short* __restrict__ xbf,
        const unsigned short* __restrict__ md_t, const unsigned short* __restrict__ wihbf,
        const float* __restrict__ bih, unsigned short* __restrict__ gi2b){
  const int tid = threadIdx.x;
  const int w = tid >> 6, l = tid & 63;
  const int c16 = l & 15, kg = l >> 4;
  const int m0 = (blockIdx.x*4 + w) * 16;
  const int mrow = m0 + c16;
  const int bb = mrow >> 9, tt = mrow & 511;
  bf16x8 a0 = *(const bf16x8*)&xbf[(size_t)mrow*32 + kg*8];
  const unsigned short* mt = md_t + (size_t)tt*4096 + bb;
  unsigned short tmp[4][8];
  #pragma unroll
  for (int f = 0; f < 4; ++f)
    #pragma unroll
    for (int e = 0; e < 8; ++e)
      tmp[f][e] = mt[(kg*8 + f*32 + e)*32];
  bf16x8 a1 = *(bf16x8*)tmp[0];
  bf16x8 a2 = *(bf16x8*)tmp[1];
  bf16x8 a3 = *(bf16x8*)tmp[2];
  bf16x8 a4 = *(bf16x8*)tmp[3];
  for (int nt2 = 0; nt2 < 8; ++nt2){
    int n0 = nt2*16;
    const unsigned short* wr = &wihbf[(size_t)(      n0 + c16)*160 + kg*8];
    const unsigned short* wz = &wihbf[(size_t)(128 + n0 + c16)*160 + kg*8];
    const unsigned short* wn = &wihbf[(size_t)(256 + n0 + c16)*160 + kg*8];
    f32x4 ar = {0.f,0.f,0.f,0.f}, az = {0.f,0.f,0.f,0.f}, an = {0.f,0.f,0.f,0.f};
    #pragma unroll
    for (int c = 0; c < 5; ++c){
      bf16x8 br = *(const bf16x8*)(wr + c*32);
      bf16x8 bz = *(const bf16x8*)(wz + c*32);
      bf16x8 bn = *(const bf16x8*)(wn + c*32);
      bf16x8 aa = (c == 0) ? a0 : (c == 1) ? a1 : (c == 2) ? a2 : (c == 3) ? a3 : a4;
      ar = __builtin_amdgcn_mfma_f32_16x16x32_bf16(aa, br, ar, 0, 0, 0);
      az = __builtin_amdgcn_mfma_f32_16x16x32_bf16(aa, bz, az, 0, 0, 0);
      an = __builtin_amdgcn_mfma_f32_16x16x32_bf16(aa, bn, an, 0, 0, 0);
    }
    float br_ = bih[n0 + c16], bz_ = bih[128 + n0 + c16], bn_ = bih[256 + n0 + c16];
    int jj = n0 + c16;
    #pragma unroll
    for (int r = 0; r < 4; ++r){
      ushort4 o = { f2bf(ar[r] + br_), f2bf(az[r] + bz_), f2bf(an[r] + bn_), 0 };
      *(ushort4*)&gi2b[(size_t)(m0 + kg*4 + r)*512 + jj*4] = o;
    }
  }
}

// ---------------- K5: GRU v13: 512 thr (8 waves), quarter-K (48 weight VGPRs -> resident),
// bf16 gi with DPP quad-broadcast, 8-step-deep prefetch.
template<int SEL>
__device__ __forceinline__ unsigned dpp_u(unsigned x){
  return (unsigned)__builtin_amdgcn_mov_dpp((int)x, SEL, 0xF, 0xF, true);
}
__device__ __forceinline__ unsigned qbc_u(unsigned x, int u){
  switch(u){
    case 0: return dpp_u<0x00>(x);
    case 1: return dpp_u<0x55>(x);
    case 2: return dpp_u<0xAA>(x);
    default: return dpp_u<0xFF>(x);
  }
}
template<int SEL>
__device__ __forceinline__ float dpp_f(float x){
  return __int_as_float(__builtin_amdgcn_mov_dpp(__float_as_int(x), SEL, 0xF, 0xF, true));
}
__global__ __launch_bounds__(512, 2) void k_gru(const unsigned short* __restrict__ gi2b,
        const _Float16* __restrict__ whh_h, const float* __restrict__ bhh,
        unsigned short* __restrict__ gout_bf){
  const int b = blockIdx.x;
  const int tid = threadIdx.x;
  const int j = tid >> 2;
  const int q = tid & 3;
  __shared__ _Float16 hs[2][144];
  const _Float16* wbr = whh_h + (size_t)(      j)*128 + q*32;
  const _Float16* wbz = whh_h + (size_t)(128 + j)*128 + q*32;
  const _Float16* wbn = whh_h + (size_t)(256 + j)*128 + q*32;
  f16x8 wr0 = *(const f16x8*)(wbr+ 0), wr1 = *(const f16x8*)(wbr+ 8),
        wr2 = *(const f16x8*)(wbr+16), wr3 = *(const f16x8*)(wbr+24);
  f16x8 wz0 = *(const f16x8*)(wbz+ 0), wz1 = *(const f16x8*)(wbz+ 8),
        wz2 = *(const f16x8*)(wbz+16), wz3 = *(const f16x8*)(wbz+24);
  f16x8 wn0 = *(const f16x8*)(wbn+ 0), wn1 = *(const f16x8*)(wbn+ 8),
        wn2 = *(const f16x8*)(wbn+16), wn3 = *(const f16x8*)(wbn+24);
  float bh_r = 0.f, bh_z = 0.f, bh_n = 0.f;
  if (!q){
    bh_r = bhh[j]; bh_z = bhh[128+j]; bh_n = bhh[256+j];
  }
  const unsigned short* gib = gi2b + (size_t)b*512*512 + j*4;
  uint2 G = *(const uint2*)(gib + (size_t)q*512);        // step-group 0, step q
  uint2 N = *(const uint2*)(gib + (size_t)(4+q)*512);    // step-group 1
  if (tid < 128) hs[0][tid] = (_Float16)0.f;
  float hprev = 0.f;
  __syncthreads();
  for (int g = 0; g < 128; ++g){
    uint2 N2 = {0u, 0u};
    if (g < 126) N2 = *(const uint2*)(gib + (size_t)(4*(g+2)+q)*512);
    #pragma unroll
    for (int u = 0; u < 4; ++u){
      const int t = g*4 + u;
      // broadcast gi (r,z in G.x; n in G.y lo16) from quad lane u
      unsigned grz = qbc_u(G.x, u);
      unsigned gn  = qbc_u(G.y, u);
      const f16x8* hq = (const f16x8*)&hs[t & 1][q*32];
      f16x8 h0 = hq[0], h1 = hq[1], h2 = hq[2], h3 = hq[3];
      float ar = 0.f, az = 0.f, an = 0.f;
      ar = dot8(wr0,h0,ar); ar = dot8(wr1,h1,ar); ar = dot8(wr2,h2,ar); ar = dot8(wr3,h3,ar);
      az = dot8(wz0,h0,az); az = dot8(wz1,h1,az); az = dot8(wz2,h2,az); az = dot8(wz3,h3,az);
      an = dot8(wn0,h0,an); an = dot8(wn1,h1,an); an = dot8(wn2,h2,an); an = dot8(wn3,h3,an);
      ar += dpp_f<0xB1>(ar); ar += dpp_f<0x4E>(ar);
      az += dpp_f<0xB1>(az); az += dpp_f<0x4E>(az);
      an += dpp_f<0xB1>(an); an += dpp_f<0x4E>(an);
      if (!q){
        float r = fsigmoid(bf2f((unsigned short)(grz & 0xFFFFu)) + ar + bh_r);
        float z = fsigmoid(bf2f((unsigned short)(grz >> 16)) + az + bh_z);
        float nn = ftanh(bf2f((unsigned short)(gn & 0xFFFFu)) + r*(an + bh_n));
        float hn = (1.f - z)*nn + z*hprev;
        hprev = hn;
        hs[(t + 1) & 1][j] = (_Float16)hn;
        gout_bf[((size_t)b*512 + t)*128 + j] = f2bf(hn);
      }
      __syncthreads();
    }
    G = N; N = N2;
  }
}

// ---------------- K6: Q,K,V = g @ [qw;kw;vw]^T + bias via bf16 MFMA (K=128)
__global__ __launch_bounds__(256) void k_mm_qkv(const unsigned short* __restrict__ gbf,
        const unsigned short* __restrict__ wbf, const float* __restrict__ qb2,
        const float* __restrict__ kb2, const float* __restrict__ vb2,
        unsigned short* __restrict__ Qbf, unsigned short* __restrict__ Kbf, float* __restrict__ Vb){
  const int tid = threadIdx.x;
  const int w = tid >> 6, l = tid & 63;
  const int c16 = l & 15, kg = l >> 4;
  const int m0 = (blockIdx.x*4 + w) * 16;
  const unsigned short* gp = &gbf[(size_t)(m0 + c16)*128 + kg*8];
  bf16x8 a0 = *(const bf16x8*)(gp + 0);
  bf16x8 a1 = *(const bf16x8*)(gp + 32);
  bf16x8 a2 = *(const bf16x8*)(gp + 64);
  bf16x8 a3 = *(const bf16x8*)(gp + 96);
  for (int nt = 0; nt < 24; ++nt){
    int n0 = nt*16;
    const unsigned short* wp = &wbf[(size_t)(n0 + c16)*128 + kg*8];
    bf16x8 b0 = *(const bf16x8*)(wp + 0);
    bf16x8 b1 = *(const bf16x8*)(wp + 32);
    bf16x8 b2 = *(const bf16x8*)(wp + 64);
    bf16x8 b3 = *(const bf16x8*)(wp + 96);
    f32x4 acc = {0.f,0.f,0.f,0.f};
    acc = __builtin_amdgcn_mfma_f32_16x16x32_bf16(a0, b0, acc, 0, 0, 0);
    acc = __builtin_amdgcn_mfma_f32_16x16x32_bf16(a1, b1, acc, 0, 0, 0);
    acc = __builtin_amdgcn_mfma_f32_16x16x32_bf16(a2, b2, acc, 0, 0, 0);
    acc = __builtin_amdgcn_mfma_f32_16x16x32_bf16(a3, b3, acc, 0, 0, 0);
    int n = n0 + c16;
    if (n < 128){
      float bias = qb2[n];
      #pragma unroll
      for (int r = 0; r < 4; ++r)
        Qbf[(size_t)(m0 + kg*4 + r)*128 + n] = f2bf(acc[r] + bias);
    } else if (n < 256){
      float bias = kb2[n-128];
      #pragma unroll
      for (int r = 0; r < 4; ++r)
        Kbf[(size_t)(m0 + kg*4 + r)*128 + (n-128)] = f2bf(acc[r] + bias);
    } else {
      float bias = vb2[n-256];
      #pragma unroll
      for (int r = 0; r < 4; ++r)
        Vb[(size_t)(m0 + kg*4 + r)*128 + (n-256)] = acc[r] + bias;
    }
  }
}

// ---------------- K7: fused attention: a = mean_t sigmoid(QK^T*sc) then out0 += a @ V (atomic)
__global__ __launch_bounds__(256) void k_attn(const unsigned short* __restrict__ Qbf,
        const unsigned short* __restrict__ Kbf, const float* __restrict__ Vb,
        float* __restrict__ out0){
  __shared__ float avs[64];
  const int tid = threadIdx.x;
  const int b  = blockIdx.x;
  const int st = blockIdx.y;
  const int w  = tid >> 6;
  const int l  = tid & 63;
  const int c16 = l & 15;
  const int kg  = l >> 4;
  const float SC = 0.08838834764831845f;
  const unsigned short* kp = Kbf + ((size_t)(b*512 + st*64 + w*16 + c16))*128 + kg*8;
  bf16x8 a0 = *(const bf16x8*)(kp + 0);
  bf16x8 a1 = *(const bf16x8*)(kp + 32);
  bf16x8 a2 = *(const bf16x8*)(kp + 64);
  bf16x8 a3 = *(const bf16x8*)(kp + 96);
  const unsigned short* qb = Qbf + ((size_t)(b*512 + c16))*128 + kg*8;
  float ps0 = 0.f, ps1 = 0.f, ps2 = 0.f, ps3 = 0.f;
  for (int tt = 0; tt < 32; ++tt){
    const unsigned short* qp = qb + (size_t)tt*16*128;
    bf16x8 b0 = *(const bf16x8*)(qp + 0);
    bf16x8 b1 = *(const bf16x8*)(qp + 32);
    bf16x8 b2 = *(const bf16x8*)(qp + 64);
    bf16x8 b3 = *(const bf16x8*)(qp + 96);
    f32x4 acc = {0.f, 0.f, 0.f, 0.f};
    acc = __builtin_amdgcn_mfma_f32_16x16x32_bf16(a0, b0, acc, 0, 0, 0);
    acc = __builtin_amdgcn_mfma_f32_16x16x32_bf16(a1, b1, acc, 0, 0, 0);
    acc = __builtin_amdgcn_mfma_f32_16x16x32_bf16(a2, b2, acc, 0, 0, 0);
    acc = __builtin_amdgcn_mfma_f32_16x16x32_bf16(a3, b3, acc, 0, 0, 0);
    ps0 += fsigmoid(acc[0]*SC);
    ps1 += fsigmoid(acc[1]*SC);
    ps2 += fsigmoid(acc[2]*SC);
    ps3 += fsigmoid(acc[3]*SC);
  }
  #pragma unroll
  for (int off = 1; off < 16; off <<= 1){
    ps0 += __shfl_xor(ps0, off);
    ps1 += __shfl_xor(ps1, off);
    ps2 += __shfl_xor(ps2, off);
    ps3 += __shfl_xor(ps3, off);
  }
  if (c16 == 0){
    int sl = w*16 + kg*4;
    avs[sl + 0] = ps0 * (1.f/512.f);
    avs[sl + 1] = ps1 * (1.f/512.f);
    avs[sl + 2] = ps2 * (1.f/512.f);
    avs[sl + 3] = ps3 * (1.f/512.f);
  }
  __syncthreads();
  const int c = tid & 127;
  const int sh = tid >> 7;
  const float* vb = Vb + ((size_t)(b*512 + st*64 + sh*32))*128 + c;
  float acc = 0.f;
  #pragma unroll 8
  for (int sl = 0; sl < 32; ++sl)
    acc += avs[sh*32 + sl] * vb[(size_t)sl*128];
  atomicAdd(&out0[b*128 + c], acc);
}

// ---------------- K9: BN3(batch) + head, 16 blocks
__global__ __launch_bounds__(256) void k_final(const float* __restrict__ out0,
        const float* __restrict__ g3, const float* __restrict__ b3,
        const float* __restrict__ hw, const float* __restrict__ hb, float* __restrict__ out){
  __shared__ float on[2][132];
  const int tid = threadIdx.x;
  const int b0 = blockIdx.x * 2;
  if (tid < 128){
    int c = tid;
    float s = 0.f;
    #pragma unroll 8
    for (int bq = 0; bq < 32; ++bq) s += out0[bq*128 + c];
    float m = s * (1.f/32.f);
    float v = 0.f;
    #pragma unroll 8
    for (int bq = 0; bq < 32; ++bq){ float d = out0[bq*128 + c] - m; v += d*d; }
    v *= (1.f/32.f);
    float sc = g3[c] * rsqrtf(v + EPSV);
    float sh = b3[c] - m*sc;
    on[0][c] = out0[(b0+0)*128 + c]*sc + sh;
    on[1][c] = out0[(b0+1)*128 + c]*sc + sh;
  }
  __syncthreads();
  for (int o = tid; o < 2*96; o += 256){
    int bl = o / 96, hh = o - bl*96;
    float acc = hb[hh];
    for (int k = 0; k < 128; ++k) acc += on[bl][k] * hw[hh*128 + k];
    out[(b0 + bl)*96 + hh] = acc;
  }
}

extern "C" void kernel_launch(void* const* d_in, const int* in_sizes, int n_in,
                              void* d_out, int out_size, void* d_ws, size_t ws_size,
                              hipStream_t stream){
  const float* x      = (const float*)d_in[0];
  const float* conv_w = (const float*)d_in[1];
  const float* conv_b = (const float*)d_in[2];
  const float* bn1_g  = (const float*)d_in[3];
  const float* bn1_b  = (const float*)d_in[4];
  const float* beta1  = (const float*)d_in[5];
  const float* bn2_g  = (const float*)d_in[6];
  const float* bn2_b  = (const float*)d_in[7];
  const float* beta2  = (const float*)d_in[8];
  const float* g_wih  = (const float*)d_in[9];
  const float* g_whh  = (const float*)d_in[10];
  const float* g_bih  = (const float*)d_in[11];
  const float* g_bhh  = (const float*)d_in[12];
  const float* q_w    = (const float*)d_in[13];
  const float* q_b    = (const float*)d_in[14];
  const float* k_w    = (const float*)d_in[15];
  const float* k_b    = (const float*)d_in[16];
  const float* v_w    = (const float*)d_in[17];
  const float* v_b    = (const float*)d_in[18];
  const float* bn3_g  = (const float*)d_in[19];
  const float* bn3_b  = (const float*)d_in[20];
  const float* head_w = (const float*)d_in[21];
  const float* head_b = (const float*)d_in[22];

  char* ws = (char*)d_ws;
  float* hp            = (float*)ws;
  unsigned short* md_t = (unsigned short*)(ws + 37748736);
  unsigned short* g_bf = (unsigned short*)(ws + 37748736);
  unsigned short* x_bf = (unsigned short*)(ws + 41943040);
  unsigned short* wih_bf  = (unsigned short*)(ws + 42991616);
  unsigned short* wqkv_bf = (unsigned short*)(ws + 43114496);
  _Float16* whh_h      = (_Float16*)(ws + 43212800);
  float* s1g  = (float*)(ws + 50331648);
  float* s2g  = (float*)(ws + 50331648 + 2048);
  float* out0 = (float*)(ws + 50331648 + 4096);
  unsigned short* gi2b = (unsigned short*)ws;
  unsigned short* Qbf  = (unsigned short*)ws;
  unsigned short* Kbf  = (unsigned short*)(ws + 4194304);
  float* Vb   = (float*)(ws + 8388608);

  (void)hipMemsetAsync(ws + 50331648, 0, 20480, stream);  // zero s1g, s2g, out0

  k_convcvt<<<1648, 256, 0, stream>>>(x, conv_w, conv_b, hp, s1g, s2g, x_bf,
                                      g_wih, q_w, k_w, v_w, g_whh, wih_bf, wqkv_bf, whh_h);
  k_lif<<<128, 32, 0, stream>>>(hp, s1g, s2g, bn1_g, bn1_b, beta1, bn2_g, bn2_b, beta2, md_t);
  k_mm_gi<<<256, 256, 0, stream>>>(x_bf, md_t, wih_bf, g_bih, gi2b);
  k_gru<<<32, 512, 0, stream>>>(gi2b, whh_h, g_bhh, g_bf);
  k_mm_qkv<<<256, 256, 0, stream>>>(g_bf, wqkv_bf, q_b, k_b, v_b, Qbf, Kbf, Vb);
  k_attn<<<dim3(32, 8), 256, 0, stream>>>(Qbf, Kbf, Vb, out0);
  k_final<<<16, 256, 0, stream>>>(out0, bn3_g, bn3_b, head_w, head_b, (float*)d_out);
}

// Round 20
// 547.137 us; speedup vs baseline: 1.2616x; 1.2616x over previous
//
#include <hip/hip_runtime.h>
#include <math.h>

#define EPSV 1e-5f

#if __has_builtin(__builtin_amdgcn_exp2f)
#define EXP2F(x) __builtin_amdgcn_exp2f(x)
#else
#define EXP2F(x) exp2f(x)
#endif
#if __has_builtin(__builtin_amdgcn_rcpf)
#define RCPF(x) __builtin_amdgcn_rcpf(x)
#else
#define RCPF(x) (1.0f/(x))
#endif

__device__ __forceinline__ float fsigmoid(float x){
  return RCPF(1.0f + EXP2F(-1.4426950408889634f * x));
}
__device__ __forceinline__ float ftanh(float x){
  return RCPF(0.5f + 0.5f * EXP2F(-2.8853900817779268f * x)) - 1.0f;
}
__device__ __forceinline__ unsigned short f2bf(float f){
  unsigned u = __float_as_uint(f);
  return (unsigned short)((u + 0x7FFFu + ((u >> 16) & 1u)) >> 16);
}
__device__ __forceinline__ float bf2f(unsigned short u){
  return __uint_as_float(((unsigned)u) << 16);
}

typedef __attribute__((ext_vector_type(8))) short bf16x8;
typedef __attribute__((ext_vector_type(4))) float f32x4;
typedef __attribute__((ext_vector_type(2))) _Float16 f16x2;
typedef __attribute__((ext_vector_type(8))) _Float16 f16x8;

#if __has_builtin(__builtin_amdgcn_fdot2)
#define FDOT2(a,b,c) __builtin_amdgcn_fdot2(a,b,c,false)
#else
__device__ __forceinline__ float FDOT2(f16x2 a, f16x2 b, float c){
  return c + (float)a[0]*(float)b[0] + (float)a[1]*(float)b[1];
}
#endif

__device__ __forceinline__ float dot8(f16x8 w, f16x8 h, float acc){
  f16x2 w0 = {w[0],w[1]}, w1 = {w[2],w[3]}, w2 = {w[4],w[5]}, w3 = {w[6],w[7]};
  f16x2 h0 = {h[0],h[1]}, h1 = {h[2],h[3]}, h2 = {h[4],h[5]}, h3 = {h[6],h[7]};
  acc = FDOT2(w0,h0,acc); acc = FDOT2(w1,h1,acc);
  acc = FDOT2(w2,h2,acc); acc = FDOT2(w3,h3,acc);
  return acc;
}

// ---------------- K1: fused conv1d(+bias, BN1 stats, x_bf emit) and weight converts.
__global__ __launch_bounds__(256) void k_convcvt(const float* __restrict__ x, const float* __restrict__ w,
        const float* __restrict__ cb, float* __restrict__ hp, float* __restrict__ s1g,
        float* __restrict__ s2g, unsigned short* __restrict__ x_bf,
        const float* __restrict__ wih, const float* __restrict__ qw, const float* __restrict__ kw,
        const float* __restrict__ vw, const float* __restrict__ whh,
        unsigned short* __restrict__ wih_bf, unsigned short* __restrict__ wqkv_bf,
        _Float16* __restrict__ whh_h){
  const int tid = threadIdx.x;
  if (blockIdx.x >= 1024){
    int i = (blockIdx.x - 1024)*256 + tid;
    if (i < 61440){ wih_bf[i] = f2bf(wih[i]); return; }
    int r = i - 61440;
    if (r < 16384){ wqkv_bf[r] = f2bf(qw[r]); return; }
    r -= 16384;
    if (r < 16384){ wqkv_bf[16384 + r] = f2bf(kw[r]); return; }
    r -= 16384;
    if (r < 16384){ wqkv_bf[32768 + r] = f2bf(vw[r]); return; }
    r -= 16384;
    if (r < 49152){ whh_h[r] = (_Float16)whh[r]; }
    return;
  }
  __shared__ float xs[32*321];
  __shared__ float ws[32*97];
  __shared__ float bs[32];
  const int t0 = (blockIdx.x >> 4) * 8;
  const int n0 = (blockIdx.x & 15) * 8;
  for (int idx = tid; idx < 32*10*32; idx += 256){
    int bq = idx / 320; int rem = idx - bq*320; int tt = rem >> 5; int i = rem & 31;
    int tg = t0 - 1 + tt;
    float v = 0.f;
    if (tg >= 0 && tg < 512) v = x[(bq*512 + tg)*32 + i];
    xs[bq*321 + tt*32 + i] = v;
  }
  for (int idx = tid; idx < 32*96; idx += 256){
    int row = idx / 96; int within = idx - row*96;
    int ss = row >> 3; int nl = row & 7;
    int c = ss*128 + n0 + nl;
    ws[row*97 + within] = w[c*96 + within];
  }
  if (tid < 32){
    int ss = tid >> 3, nl = tid & 7;
    bs[tid] = cb[ss*128 + n0 + nl];
  }
  __syncthreads();
  if ((blockIdx.x & 15) == 0){
    for (int idx = tid; idx < 32*8*32; idx += 256){
      int bq = idx >> 8; int rem = idx & 255; int tt = rem >> 5; int i = rem & 31;
      x_bf[(bq*512 + t0 + tt)*32 + i] = f2bf(xs[bq*321 + (tt+1)*32 + i]);
    }
  }
  const int b = tid & 31;
  const int nl = tid >> 5;
  float acc[4][8];
  #pragma unroll
  for (int ss = 0; ss < 4; ++ss){
    float bv = bs[ss*8 + nl];
    #pragma unroll
    for (int t = 0; t < 8; ++t) acc[ss][t] = bv;
  }
  for (int i = 0; i < 32; ++i){
    #pragma unroll
    for (int k = 0; k < 3; ++k){
      float w0 = ws[(0*8+nl)*97 + i*3 + k];
      float w1 = ws[(1*8+nl)*97 + i*3 + k];
      float w2 = ws[(2*8+nl)*97 + i*3 + k];
      float w3 = ws[(3*8+nl)*97 + i*3 + k];
      #pragma unroll
      for (int t = 0; t < 8; ++t){
        float xv = xs[b*321 + (t+k)*32 + i];
        acc[0][t] += xv*w0; acc[1][t] += xv*w1; acc[2][t] += xv*w2; acc[3][t] += xv*w3;
      }
    }
  }
  #pragma unroll
  for (int ss = 0; ss < 4; ++ss){
    int n = n0 + nl;
    float s1 = 0.f, s2 = 0.f;
    #pragma unroll
    for (int t = 0; t < 8; ++t){
      float v = acc[ss][t];
      int s = (t0 + t)*4 + ss;
      hp[s*4096 + n*32 + b] = v;
      s1 += v; s2 += v*v;
    }
    #pragma unroll
    for (int off = 1; off < 32; off <<= 1){
      s1 += __shfl_xor(s1, off);
      s2 += __shfl_xor(s2, off);
    }
    if (b == 0){
      int c = ss*128 + n;
      atomicAdd(&s1g[c], s1);
      atomicAdd(&s2g[c], s2);
    }
  }
}

// ---------------- K3: fused BN1-finalize + BN1-apply + LIF1 + BN2 + LIF2 + downsample -> md_t
// 64 blocks x 64 threads; 3-deep hp prefetch; per-block BN1 coeffs derived inline.
__global__ __launch_bounds__(64) void k_lif(const float* __restrict__ hp,
        const float* __restrict__ s1g, const float* __restrict__ s2g,
        const float* __restrict__ g1v, const float* __restrict__ b1v,
        const float* __restrict__ beta1, const float* __restrict__ g2v, const float* __restrict__ b2v,
        const float* __restrict__ beta2, unsigned short* __restrict__ md_t){
  const int tid = threadIdx.x;
  const int b = tid & 31;
  const int n = blockIdx.x * 2 + (tid >> 5);
  float a1r[4], b1r[4];
  #pragma unroll
  for (int ss = 0; ss < 4; ++ss){
    int c = ss*128 + n;
    float m = s1g[c] * (1.f/16384.f);
    float v = s2g[c] * (1.f/16384.f) - m*m;
    float sc = g1v[c] * rsqrtf(v + EPSV);
    a1r[ss] = sc;
    b1r[ss] = b1v[c] - m*sc;
  }
  float be1 = fminf(fmaxf(beta1[n], 0.f), 0.99f);
  float be2 = fminf(fmaxf(beta2[n], 0.f), 0.99f);
  float g2 = g2v[n], bb2 = b2v[n];
  float m1 = 0.f, r1 = 0.f, m2 = 0.f, r2 = 0.f;
  const float* base = hp + n*32 + b;
  float c0 = base[0], c1 = base[4096], c2 = base[2*4096], c3 = base[3*4096];
  const float* p1 = base + 16384;
  float d0 = p1[0], d1 = p1[4096], d2 = p1[2*4096], d3 = p1[3*4096];
  const float* p2 = base + 2*16384;
  float e0 = p2[0], e1 = p2[4096], e2 = p2[2*4096], e3 = p2[3*4096];

#define LIF_STEP(CV, A1R, B1R) { \
    float x1 = CV*A1R + B1R; \
    m1 = be1*m1 + x1 - r1; \
    bool sp = (m1 > 1.0f); \
    unsigned long long mk = __ballot(sp); \
    float spk = sp ? 1.f : 0.f; r1 = spk; \
    unsigned hf = (tid & 32) ? (unsigned)(mk >> 32) : (unsigned)mk; \
    float mean = (float)__popc(hf) * 0.03125f; \
    float var = mean - mean*mean; \
    float h2 = (spk - mean) * rsqrtf(var + EPSV) * g2 + bb2; \
    m2 = be2*m2 + h2 - r2; \
    r2 = (m2 > 1.0f) ? 1.f : 0.f; \
    accd += m2; }

  for (int t = 0; t < 512; ++t){
    float f0 = 0.f, f1 = 0.f, f2 = 0.f, f3 = 0.f;
    if (t < 509){
      const float* nb = base + (size_t)(t+3)*16384;
      f0 = nb[0]; f1 = nb[4096]; f2 = nb[2*4096]; f3 = nb[3*4096];
    }
    float accd = 0.f;
    LIF_STEP(c0, a1r[0], b1r[0])
    LIF_STEP(c1, a1r[1], b1r[1])
    LIF_STEP(c2, a1r[2], b1r[2])
    LIF_STEP(c3, a1r[3], b1r[3])
    md_t[((t*128) + n)*32 + b] = f2bf(accd * 0.25f);
    c0 = d0; c1 = d1; c2 = d2; c3 = d3;
    d0 = e0; d1 = e1; d2 = e2; d3 = e3;
    e0 = f0; e1 = f1; e2 = f2; e3 = f3;
  }
#undef LIF_STEP
}

// ---------------- K4: gi2b (bf16 ushort4 {r,z,n,0}) = concat(x, md) @ W_ih^T + b_ih via MFMA.
__global__ __launch_bounds__(256) void k_mm_gi(const unsigned short* __restrict__ xbf,
        const unsigned short* __restrict__ md_t, const unsigned short* __restrict__ wihbf,
        const float* __restrict__ bih, unsigned short* __restrict__ gi2b){
  const int tid = threadIdx.x;
  const int w = tid >> 6, l = tid & 63;
  const int c16 = l & 15, kg = l >> 4;
  const int m0 = (blockIdx.x*4 + w) * 16;
  const int mrow = m0 + c16;
  const int bb = mrow >> 9, tt = mrow & 511;
  bf16x8 a0 = *(const bf16x8*)&xbf[(size_t)mrow*32 + kg*8];
  const unsigned short* mt = md_t + (size_t)tt*4096 + bb;
  unsigned short tmp[4][8];
  #pragma unroll
  for (int f = 0; f < 4; ++f)
    #pragma unroll
    for (int e = 0; e < 8; ++e)
      tmp[f][e] = mt[(kg*8 + f*32 + e)*32];
  bf16x8 a1 = *(bf16x8*)tmp[0];
  bf16x8 a2 = *(bf16x8*)tmp[1];
  bf16x8 a3 = *(bf16x8*)tmp[2];
  bf16x8 a4 = *(bf16x8*)tmp[3];
  for (int nt2 = 0; nt2 < 8; ++nt2){
    int n0 = nt2*16;
    const unsigned short* wr = &wihbf[(size_t)(      n0 + c16)*160 + kg*8];
    const unsigned short* wz = &wihbf[(size_t)(128 + n0 + c16)*160 + kg*8];
    const unsigned short* wn = &wihbf[(size_t)(256 + n0 + c16)*160 + kg*8];
    f32x4 ar = {0.f,0.f,0.f,0.f}, az = {0.f,0.f,0.f,0.f}, an = {0.f,0.f,0.f,0.f};
    #pragma unroll
    for (int c = 0; c < 5; ++c){
      bf16x8 br = *(const bf16x8*)(wr + c*32);
      bf16x8 bz = *(const bf16x8*)(wz + c*32);
      bf16x8 bn = *(const bf16x8*)(wn + c*32);
      bf16x8 aa = (c == 0) ? a0 : (c == 1) ? a1 : (c == 2) ? a2 : (c == 3) ? a3 : a4;
      ar = __builtin_amdgcn_mfma_f32_16x16x32_bf16(aa, br, ar, 0, 0, 0);
      az = __builtin_amdgcn_mfma_f32_16x16x32_bf16(aa, bz, az, 0, 0, 0);
      an = __builtin_amdgcn_mfma_f32_16x16x32_bf16(aa, bn, an, 0, 0, 0);
    }
    float br_ = bih[n0 + c16], bz_ = bih[128 + n0 + c16], bn_ = bih[256 + n0 + c16];
    int jj = n0 + c16;
    #pragma unroll
    for (int r = 0; r < 4; ++r){
      ushort4 o = { f2bf(ar[r] + br_), f2bf(az[r] + bz_), f2bf(an[r] + bn_), 0 };
      *(ushort4*)&gi2b[(size_t)(m0 + kg*4 + r)*512 + jj*4] = o;
    }
  }
}

// ---------------- K5: GRU v11 (R18 best): bf16 gi stream, f16 dot2, 256 threads (4 waves),
// half-K split, 8-deep prefetch.
template<int SEL>
__device__ __forceinline__ float dpp_qp(float x){
  return __int_as_float(__builtin_amdgcn_mov_dpp(__float_as_int(x), SEL, 0xF, 0xF, true));
}
__global__ __launch_bounds__(256, 1) void k_gru(const unsigned short* __restrict__ gi2b,
        const _Float16* __restrict__ whh_h, const float* __restrict__ bhh,
        unsigned short* __restrict__ gout_bf){
  const int b = blockIdx.x;
  const int tid = threadIdx.x;
  const int j = tid >> 1;
  const int half = tid & 1;
  const int k0 = half * 64;
  __shared__ _Float16 hs[2][144];
  const _Float16* wbr = whh_h + (size_t)(      j)*128 + k0;
  const _Float16* wbz = whh_h + (size_t)(128 + j)*128 + k0;
  const _Float16* wbn = whh_h + (size_t)(256 + j)*128 + k0;
  f16x8 wr[8], wz[8], wn[8];
  #pragma unroll
  for (int i = 0; i < 8; ++i){
    wr[i] = *(const f16x8*)(wbr + i*8);
    wz[i] = *(const f16x8*)(wbz + i*8);
    wn[i] = *(const f16x8*)(wbn + i*8);
  }
  float bh_r = 0.f, bh_z = 0.f, bh_n = 0.f;
  if (!half){
    bh_r = bhh[j]; bh_z = bhh[128+j]; bh_n = bhh[256+j];
  }
  const unsigned short* gib = gi2b + (size_t)b*512*512 + j*4;
  ushort4 G[4], N[4];
  #pragma unroll
  for (int u = 0; u < 4; ++u){
    G[u] = *(const ushort4*)(gib + (size_t)u*512);
    N[u] = *(const ushort4*)(gib + (size_t)(4+u)*512);
  }
  if (tid < 128) hs[0][tid] = (_Float16)0.f;
  float hprev = 0.f;
  __syncthreads();
  for (int g = 0; g < 128; ++g){
    ushort4 N2[4];
    if (g < 126){
      #pragma unroll
      for (int u = 0; u < 4; ++u)
        N2[u] = *(const ushort4*)(gib + (size_t)(4*(g+2)+u)*512);
    } else {
      #pragma unroll
      for (int u = 0; u < 4; ++u) N2[u] = (ushort4){0,0,0,0};
    }
    #pragma unroll
    for (int u = 0; u < 4; ++u){
      const int t = g*4 + u;
      const f16x8* hq = (const f16x8*)&hs[t & 1][k0];
      f16x8 h0 = hq[0], h1 = hq[1], h2 = hq[2], h3 = hq[3],
            h4 = hq[4], h5 = hq[5], h6 = hq[6], h7 = hq[7];
      float ar0 = 0.f, ar1 = 0.f, az0 = 0.f, az1 = 0.f, an0 = 0.f, an1 = 0.f;
      ar0 = dot8(wr[0],h0,ar0); ar0 = dot8(wr[1],h1,ar0); ar0 = dot8(wr[2],h2,ar0); ar0 = dot8(wr[3],h3,ar0);
      ar1 = dot8(wr[4],h4,ar1); ar1 = dot8(wr[5],h5,ar1); ar1 = dot8(wr[6],h6,ar1); ar1 = dot8(wr[7],h7,ar1);
      az0 = dot8(wz[0],h0,az0); az0 = dot8(wz[1],h1,az0); az0 = dot8(wz[2],h2,az0); az0 = dot8(wz[3],h3,az0);
      az1 = dot8(wz[4],h4,az1); az1 = dot8(wz[5],h5,az1); az1 = dot8(wz[6],h6,az1); az1 = dot8(wz[7],h7,az1);
      an0 = dot8(wn[0],h0,an0); an0 = dot8(wn[1],h1,an0); an0 = dot8(wn[2],h2,an0); an0 = dot8(wn[3],h3,an0);
      an1 = dot8(wn[4],h4,an1); an1 = dot8(wn[5],h5,an1); an1 = dot8(wn[6],h6,an1); an1 = dot8(wn[7],h7,an1);
      float ar = ar0 + ar1, az = az0 + az1, an = an0 + an1;
      ar += dpp_qp<0xB1>(ar);
      az += dpp_qp<0xB1>(az);
      an += dpp_qp<0xB1>(an);
      if (!half){
        float r = fsigmoid(bf2f(G[u].x) + ar + bh_r);
        float z = fsigmoid(bf2f(G[u].y) + az + bh_z);
        float nn = ftanh(bf2f(G[u].z) + r*(an + bh_n));
        float hn = (1.f - z)*nn + z*hprev;
        hprev = hn;
        hs[(t + 1) & 1][j] = (_Float16)hn;
        gout_bf[((size_t)b*512 + t)*128 + j] = f2bf(hn);
      }
      __syncthreads();
    }
    #pragma unroll
    for (int u = 0; u < 4; ++u){ G[u] = N[u]; N[u] = N2[u]; }
  }
}

// ---------------- K6: Q,K,V = g @ [qw;kw;vw]^T + bias via bf16 MFMA (K=128)
__global__ __launch_bounds__(256) void k_mm_qkv(const unsigned short* __restrict__ gbf,
        const unsigned short* __restrict__ wbf, const float* __restrict__ qb2,
        const float* __restrict__ kb2, const float* __restrict__ vb2,
        unsigned short* __restrict__ Qbf, unsigned short* __restrict__ Kbf, float* __restrict__ Vb){
  const int tid = threadIdx.x;
  const int w = tid >> 6, l = tid & 63;
  const int c16 = l & 15, kg = l >> 4;
  const int m0 = (blockIdx.x*4 + w) * 16;
  const unsigned short* gp = &gbf[(size_t)(m0 + c16)*128 + kg*8];
  bf16x8 a0 = *(const bf16x8*)(gp + 0);
  bf16x8 a1 = *(const bf16x8*)(gp + 32);
  bf16x8 a2 = *(const bf16x8*)(gp + 64);
  bf16x8 a3 = *(const bf16x8*)(gp + 96);
  for (int nt = 0; nt < 24; ++nt){
    int n0 = nt*16;
    const unsigned short* wp = &wbf[(size_t)(n0 + c16)*128 + kg*8];
    bf16x8 b0 = *(const bf16x8*)(wp + 0);
    bf16x8 b1 = *(const bf16x8*)(wp + 32);
    bf16x8 b2 = *(const bf16x8*)(wp + 64);
    bf16x8 b3 = *(const bf16x8*)(wp + 96);
    f32x4 acc = {0.f,0.f,0.f,0.f};
    acc = __builtin_amdgcn_mfma_f32_16x16x32_bf16(a0, b0, acc, 0, 0, 0);
    acc = __builtin_amdgcn_mfma_f32_16x16x32_bf16(a1, b1, acc, 0, 0, 0);
    acc = __builtin_amdgcn_mfma_f32_16x16x32_bf16(a2, b2, acc, 0, 0, 0);
    acc = __builtin_amdgcn_mfma_f32_16x16x32_bf16(a3, b3, acc, 0, 0, 0);
    int n = n0 + c16;
    if (n < 128){
      float bias = qb2[n];
      #pragma unroll
      for (int r = 0; r < 4; ++r)
        Qbf[(size_t)(m0 + kg*4 + r)*128 + n] = f2bf(acc[r] + bias);
    } else if (n < 256){
      float bias = kb2[n-128];
      #pragma unroll
      for (int r = 0; r < 4; ++r)
        Kbf[(size_t)(m0 + kg*4 + r)*128 + (n-128)] = f2bf(acc[r] + bias);
    } else {
      float bias = vb2[n-256];
      #pragma unroll
      for (int r = 0; r < 4; ++r)
        Vb[(size_t)(m0 + kg*4 + r)*128 + (n-256)] = acc[r] + bias;
    }
  }
}

// ---------------- K7: fused attention: a = mean_t sigmoid(QK^T*sc) then out0 += a @ V (atomic)
__global__ __launch_bounds__(256) void k_attn(const unsigned short* __restrict__ Qbf,
        const unsigned short* __restrict__ Kbf, const float* __restrict__ Vb,
        float* __restrict__ out0){
  __shared__ float avs[64];
  const int tid = threadIdx.x;
  const int b  = blockIdx.x;
  const int st = blockIdx.y;
  const int w  = tid >> 6;
  const int l  = tid & 63;
  const int c16 = l & 15;
  const int kg  = l >> 4;
  const float SC = 0.08838834764831845f;
  const unsigned short* kp = Kbf + ((size_t)(b*512 + st*64 + w*16 + c16))*128 + kg*8;
  bf16x8 a0 = *(const bf16x8*)(kp + 0);
  bf16x8 a1 = *(const bf16x8*)(kp + 32);
  bf16x8 a2 = *(const bf16x8*)(kp + 64);
  bf16x8 a3 = *(const bf16x8*)(kp + 96);
  const unsigned short* qb = Qbf + ((size_t)(b*512 + c16))*128 + kg*8;
  float ps0 = 0.f, ps1 = 0.f, ps2 = 0.f, ps3 = 0.f;
  for (int tt = 0; tt < 32; ++tt){
    const unsigned short* qp = qb + (size_t)tt*16*128;
    bf16x8 b0 = *(const bf16x8*)(qp + 0);
    bf16x8 b1 = *(const bf16x8*)(qp + 32);
    bf16x8 b2 = *(const bf16x8*)(qp + 64);
    bf16x8 b3 = *(const bf16x8*)(qp + 96);
    f32x4 acc = {0.f, 0.f, 0.f, 0.f};
    acc = __builtin_amdgcn_mfma_f32_16x16x32_bf16(a0, b0, acc, 0, 0, 0);
    acc = __builtin_amdgcn_mfma_f32_16x16x32_bf16(a1, b1, acc, 0, 0, 0);
    acc = __builtin_amdgcn_mfma_f32_16x16x32_bf16(a2, b2, acc, 0, 0, 0);
    acc = __builtin_amdgcn_mfma_f32_16x16x32_bf16(a3, b3, acc, 0, 0, 0);
    ps0 += fsigmoid(acc[0]*SC);
    ps1 += fsigmoid(acc[1]*SC);
    ps2 += fsigmoid(acc[2]*SC);
    ps3 += fsigmoid(acc[3]*SC);
  }
  #pragma unroll
  for (int off = 1; off < 16; off <<= 1){
    ps0 += __shfl_xor(ps0, off);
    ps1 += __shfl_xor(ps1, off);
    ps2 += __shfl_xor(ps2, off);
    ps3 += __shfl_xor(ps3, off);
  }
  if (c16 == 0){
    int sl = w*16 + kg*4;
    avs[sl + 0] = ps0 * (1.f/512.f);
    avs[sl + 1] = ps1 * (1.f/512.f);
    avs[sl + 2] = ps2 * (1.f/512.f);
    avs[sl + 3] = ps3 * (1.f/512.f);
  }
  __syncthreads();
  const int c = tid & 127;
  const int sh = tid >> 7;
  const float* vb = Vb + ((size_t)(b*512 + st*64 + sh*32))*128 + c;
  float acc = 0.f;
  #pragma unroll 8
  for (int sl = 0; sl < 32; ++sl)
    acc += avs[sh*32 + sl] * vb[(size_t)sl*128];
  atomicAdd(&out0[b*128 + c], acc);
}

// ---------------- K9: BN3(batch) + head, 16 blocks
__global__ __launch_bounds__(256) void k_final(const float* __restrict__ out0,
        const float* __restrict__ g3, const float* __restrict__ b3,
        const float* __restrict__ hw, const float* __restrict__ hb, float* __restrict__ out){
  __shared__ float on[2][132];
  const int tid = threadIdx.x;
  const int b0 = blockIdx.x * 2;
  if (tid < 128){
    int c = tid;
    float s = 0.f;
    #pragma unroll 8
    for (int bq = 0; bq < 32; ++bq) s += out0[bq*128 + c];
    float m = s * (1.f/32.f);
    float v = 0.f;
    #pragma unroll 8
    for (int bq = 0; bq < 32; ++bq){ float d = out0[bq*128 + c] - m; v += d*d; }
    v *= (1.f/32.f);
    float sc = g3[c] * rsqrtf(v + EPSV);
    float sh = b3[c] - m*sc;
    on[0][c] = out0[(b0+0)*128 + c]*sc + sh;
    on[1][c] = out0[(b0+1)*128 + c]*sc + sh;
  }
  __syncthreads();
  for (int o = tid; o < 2*96; o += 256){
    int bl = o / 96, hh = o - bl*96;
    float acc = hb[hh];
    for (int k = 0; k < 128; ++k) acc += on[bl][k] * hw[hh*128 + k];
    out[(b0 + bl)*96 + hh] = acc;
  }
}

extern "C" void kernel_launch(void* const* d_in, const int* in_sizes, int n_in,
                              void* d_out, int out_size, void* d_ws, size_t ws_size,
                              hipStream_t stream){
  const float* x      = (const float*)d_in[0];
  const float* conv_w = (const float*)d_in[1];
  const float* conv_b = (const float*)d_in[2];
  const float* bn1_g  = (const float*)d_in[3];
  const float* bn1_b  = (const float*)d_in[4];
  const float* beta1  = (const float*)d_in[5];
  const float* bn2_g  = (const float*)d_in[6];
  const float* bn2_b  = (const float*)d_in[7];
  const float* beta2  = (const float*)d_in[8];
  const float* g_wih  = (const float*)d_in[9];
  const float* g_whh  = (const float*)d_in[10];
  const float* g_bih  = (const float*)d_in[11];
  const float* g_bhh  = (const float*)d_in[12];
  const float* q_w    = (const float*)d_in[13];
  const float* q_b    = (const float*)d_in[14];
  const float* k_w    = (const float*)d_in[15];
  const float* k_b    = (const float*)d_in[16];
  const float* v_w    = (const float*)d_in[17];
  const float* v_b    = (const float*)d_in[18];
  const float* bn3_g  = (const float*)d_in[19];
  const float* bn3_b  = (const float*)d_in[20];
  const float* head_w = (const float*)d_in[21];
  const float* head_b = (const float*)d_in[22];

  char* ws = (char*)d_ws;
  float* hp            = (float*)ws;
  unsigned short* md_t = (unsigned short*)(ws + 37748736);
  unsigned short* g_bf = (unsigned short*)(ws + 37748736);
  unsigned short* x_bf = (unsigned short*)(ws + 41943040);
  unsigned short* wih_bf  = (unsigned short*)(ws + 42991616);
  unsigned short* wqkv_bf = (unsigned short*)(ws + 43114496);
  _Float16* whh_h      = (_Float16*)(ws + 43212800);
  float* s1g  = (float*)(ws + 50331648);
  float* s2g  = (float*)(ws + 50331648 + 2048);
  float* out0 = (float*)(ws + 50331648 + 4096);
  unsigned short* gi2b = (unsigned short*)ws;
  unsigned short* Qbf  = (unsigned short*)ws;
  unsigned short* Kbf  = (unsigned short*)(ws + 4194304);
  float* Vb   = (float*)(ws + 8388608);

  (void)hipMemsetAsync(ws + 50331648, 0, 20480, stream);  // zero s1g, s2g, out0

  k_convcvt<<<1648, 256, 0, stream>>>(x, conv_w, conv_b, hp, s1g, s2g, x_bf,
                                      g_wih, q_w, k_w, v_w, g_whh, wih_bf, wqkv_bf, whh_h);
  k_lif<<<64, 64, 0, stream>>>(hp, s1g, s2g, bn1_g, bn1_b, beta1, bn2_g, bn2_b, beta2, md_t);
  k_mm_gi<<<256, 256, 0, stream>>>(x_bf, md_t, wih_bf, g_bih, gi2b);
  k_gru<<<32, 256, 0, stream>>>(gi2b, whh_h, g_bhh, g_bf);
  k_mm_qkv<<<256, 256, 0, stream>>>(g_bf, wqkv_bf, q_b, k_b, v_b, Qbf, Kbf, Vb);
  k_attn<<<dim3(32, 8), 256, 0, stream>>>(Qbf, Kbf, Vb, out0);
  k_final<<<16, 256, 0, stream>>>(out0, bn3_g, bn3_b, head_w, head_b, (float*)d_out);
}